// Round 1
// baseline (206.903 us; speedup 1.0000x reference)
//
#include <hip/hip_runtime.h>

// Problem constants (from reference)
#define NS   4096            // N_SAMPLES
#define NW   64              // N_WIDTH
#define NNODES 257           // N_NODES
#define SW   (NS * NW)       // 262144
#define ROW  (NW * NNODES)   // 16448 floats per sample region in each big array
#define SWN  (NS * NW * NNODES)  // 67,371,008

__global__ __launch_bounds__(256) void kann_fused_kernel(
    const float* __restrict__ x,
    const float* __restrict__ weight,   // [64, 257]
    float* __restrict__ out)
{
    const int i   = blockIdx.x;       // sample
    const int tid = threadIdx.x;

    __shared__ float s_b[15];         // phi[5], dphi[5], ddphi[5]
    __shared__ int   s_base;

    // ---- per-sample basis (computed redundantly by all threads; cheap) ----
    const float xi = x[i];
    const float x_shift = 256.0f * xi;                 // (N_NODES-1)*(x-0)/1
    float fel = floorf(x_shift * 0.25f);               // floor(x_shift / N_ORDER)
    fel = fminf(fmaxf(fel, 0.0f), 63.0f);              // clip to [0, N_ELEMENTS-1]
    const int base = (int)fel * 4;                     // nodes_in_l
    const float xt = 0.5f * (x_shift - (float)base) - 1.0f;

    const float nd[5] = {-1.0f, -0.5f, 0.0f, 0.5f, 1.0f};
    float phi[5], dphi[5], ddphi[5];

    #pragma unroll
    for (int j = 0; j < 5; ++j) {
        // phi
        float p = 1.0f;
        #pragma unroll
        for (int m = 0; m < 5; ++m)
            if (m != j) p = p * (xt - nd[m]) / (nd[j] - nd[m]);
        phi[j] = p;
        // dphi
        float y1 = 0.0f;
        #pragma unroll
        for (int ii = 0; ii < 5; ++ii) {
            if (ii != j) {
                float k = 1.0f / (nd[j] - nd[ii]);
                #pragma unroll
                for (int m = 0; m < 5; ++m)
                    if (m != ii && m != j) k = k * (xt - nd[m]) / (nd[j] - nd[m]);
                y1 += k;
            }
        }
        dphi[j] = y1 * 128.0f;                         // / delta_x
        // ddphi
        float y2 = 0.0f;
        #pragma unroll
        for (int ii = 0; ii < 5; ++ii) {
            if (ii != j) {
                float ks = 0.0f;
                #pragma unroll
                for (int m = 0; m < 5; ++m) {
                    if (m != ii && m != j) {
                        float kp = 1.0f / (nd[j] - nd[m]);
                        #pragma unroll
                        for (int n = 0; n < 5; ++n)
                            if (n != ii && n != j && n != m)
                                kp = kp * (xt - nd[n]) / (nd[j] - nd[n]);
                        ks += kp;
                    }
                }
                y2 += ks / (nd[j] - nd[ii]);
            }
        }
        ddphi[j] = y2 * 16384.0f;                      // / delta_x^2
    }

    if (tid == 0) {
        #pragma unroll
        for (int j = 0; j < 5; ++j) {
            s_b[j]      = phi[j];
            s_b[5 + j]  = dphi[j];
            s_b[10 + j] = ddphi[j];
        }
        s_base = base;
    }

    // ---- output pointers ----
    float* t_out   = out;
    float* dt_out  = out + SW;
    float* ddt_out = out + 2 * (size_t)SW;
    float* big     = out + 3 * (size_t)SW;             // 3 arrays of SWN

    // ---- t / dt / ddt: thread k<64 does the 5-term dot products ----
    if (tid < NW) {
        const float* wrow = weight + tid * NNODES + base;
        float t = 0.0f, dt = 0.0f, ddt = 0.0f;
        #pragma unroll
        for (int j = 0; j < 5; ++j) {
            const float w = wrow[j];
            t   += w * phi[j];
            dt  += w * dphi[j];
            ddt += w * ddphi[j];
        }
        t_out[i * NW + tid]   = t;
        dt_out[i * NW + tid]  = dt;
        ddt_out[i * NW + tid] = ddt;
    }

    if (i == 0 && tid == 0) {
        out[3 * (size_t)SW + 3 * (size_t)SWN] = 0.0078125f;  // delta_x
    }

    // ---- zero-fill this sample's region in all 3 big arrays (float4) ----
    const float4 z = make_float4(0.0f, 0.0f, 0.0f, 0.0f);
    #pragma unroll
    for (int a = 0; a < 3; ++a) {
        float4* reg = reinterpret_cast<float4*>(
            big + (size_t)a * SWN + (size_t)i * ROW);
        for (int f4 = tid; f4 < ROW / 4; f4 += 256) {  // 4112 float4 per array
            reg[f4] = z;
        }
    }

    __syncthreads();   // zeros + s_b visible to whole block

    // ---- scatter the 3 x 64 x 5 nonzeros (values from LDS; static-safe) ----
    const int b = s_base;
    #pragma unroll
    for (int a = 0; a < 3; ++a) {
        float* reg = big + (size_t)a * SWN + (size_t)i * ROW;
        for (int t = tid; t < NW * 5; t += 256) {      // 320 tasks
            const int k = t / 5;
            const int j = t - k * 5;
            reg[k * NNODES + b + j] = s_b[a * 5 + j];
        }
    }
}

extern "C" void kernel_launch(void* const* d_in, const int* in_sizes, int n_in,
                              void* d_out, int out_size, void* d_ws, size_t ws_size,
                              hipStream_t stream) {
    const float* x      = (const float*)d_in[0];
    const float* weight = (const float*)d_in[1];
    float* out          = (float*)d_out;
    kann_fused_kernel<<<NS, 256, 0, stream>>>(x, weight, out);
}